// Round 3
// baseline (1034.783 us; speedup 1.0000x reference)
//
#include <hip/hip_runtime.h>

typedef unsigned short u16;
typedef __attribute__((ext_vector_type(4))) float f32x4;
using bf16x8 = __attribute__((ext_vector_type(8))) short;
typedef __attribute__((ext_vector_type(8))) unsigned short u16x8;
typedef __attribute__((ext_vector_type(4))) unsigned short u16x4;

__device__ __forceinline__ float bf2f(u16 u) {
  unsigned v = ((unsigned)u) << 16;
  float f;
  __builtin_memcpy(&f, &v, 4);
  return f;
}
__device__ __forceinline__ u16 f2bf(float f) {
  unsigned u;
  __builtin_memcpy(&u, &f, 4);
  u += 0x7fffu + ((u >> 16) & 1u);
  return (u16)(u >> 16);
}

// ---------------- x (fp32) -> xb (bf16) ----------------
__global__ void cvtx_k(const float* __restrict__ x, u16* __restrict__ xb) {
  const long i = (long)blockIdx.x * 256 + threadIdx.x;  // chunk of 4
  f32x4 v = *(const f32x4*)(x + i * 4);
  u16x4 r;
#pragma unroll
  for (int j = 0; j < 4; ++j) r[j] = f2bf(v[j]);
  *(u16x4*)(xb + i * 4) = r;
}

// ---------------- router: 1 wave per token, fp32 ----------------
__global__ __launch_bounds__(64) void router_k(const float* __restrict__ x,
    const float* __restrict__ rw, const float* __restrict__ rb,
    int* __restrict__ topk_idx, float* __restrict__ topk_w, int* __restrict__ ib) {
  const int t = blockIdx.x, lane = threadIdx.x;
  const float* xr = x + (long)t * 1024 + lane * 16;
  float xf[16];
#pragma unroll
  for (int j = 0; j < 4; ++j) {
    f32x4 v = *(const f32x4*)(xr + j * 4);
#pragma unroll
    for (int q = 0; q < 4; ++q) xf[j * 4 + q] = v[q];
  }
  float acc[16];
#pragma unroll
  for (int ee = 0; ee < 16; ++ee) acc[ee] = 0.f;
  const float* wr = rw + lane * 256;  // 16 rows of router_w (H-major, 16 wide)
#pragma unroll
  for (int j = 0; j < 16; ++j) {
#pragma unroll
    for (int q = 0; q < 4; ++q) {
      f32x4 w = *(const f32x4*)(wr + j * 16 + q * 4);
#pragma unroll
      for (int ee = 0; ee < 4; ++ee) acc[q * 4 + ee] += xf[j] * w[ee];
    }
  }
#pragma unroll
  for (int off = 32; off > 0; off >>= 1)
#pragma unroll
    for (int ee = 0; ee < 16; ++ee) acc[ee] += __shfl_down(acc[ee], off);
  if (lane == 0) {
    float p[16]; float mx = -1e30f;
#pragma unroll
    for (int ee = 0; ee < 16; ++ee) { p[ee] = acc[ee] + rb[ee]; mx = fmaxf(mx, p[ee]); }
    float sum = 0.f;
#pragma unroll
    for (int ee = 0; ee < 16; ++ee) { p[ee] = __expf(p[ee] - mx); sum += p[ee]; }
    int i0 = 0; float p0 = p[0];
    for (int ee = 1; ee < 16; ++ee) if (p[ee] > p0) { p0 = p[ee]; i0 = ee; }
    int i1 = -1; float p1 = -1.f;
    for (int ee = 0; ee < 16; ++ee) if (ee != i0 && p[ee] > p1) { p1 = p[ee]; i1 = ee; }
    const float inv = 1.f / sum;
    p0 *= inv; p1 *= inv;
    const float d = p0 + p1 + 1e-6f;
    topk_idx[t * 2] = i0; topk_idx[t * 2 + 1] = i1;
    topk_w[t * 2] = p0 / d;
    topk_w[t * 2 + 1] = p1 / d;
    if (i0 < 15) atomicAdd(&ib[i0], 1);
    if (i1 < 15) atomicAdd(&ib[i1], 1);
  }
}

// ib layout: [0..15] counts, [16..31] offsets (offs[15]=total), [32..47] cursors,
//            [48] n_mtiles, [64..] mtile table {expert,row0,row_end,pad}
__global__ void zero_k(int* __restrict__ ib) {
  if (threadIdx.x < 16) ib[threadIdx.x] = 0;
}

__global__ void scan_k(int* __restrict__ ib) {
  if (threadIdx.x != 0 || blockIdx.x != 0) return;
  int off = 0;
  for (int ee = 0; ee < 15; ++ee) { ib[16 + ee] = off; ib[32 + ee] = off; off += ib[ee]; }
  ib[16 + 15] = off;
  int nm = 0;
  for (int ee = 0; ee < 15; ++ee) {
    const int st = ib[16 + ee], en = ib[16 + ee + 1];
    for (int r = st; r < en; r += 128) {
      ib[64 + nm * 4] = ee; ib[64 + nm * 4 + 1] = r; ib[64 + nm * 4 + 2] = en; ++nm;
    }
  }
  ib[48] = nm;
}

__global__ void scatter_k(const int* __restrict__ topk_idx, const float* __restrict__ topk_w,
                          int* __restrict__ ib, int* __restrict__ tok_ids,
                          float* __restrict__ tok_w, int* __restrict__ slot_map) {
  const int j = blockIdx.x * 256 + threadIdx.x;
  if (j >= 32768) return;
  const int ee = topk_idx[j];
  if (ee < 15) {
    const int pos = atomicAdd(&ib[32 + ee], 1);
    tok_ids[pos] = j >> 1;
    tok_w[pos] = topk_w[j];
    slot_map[j] = pos;
  } else {
    slot_map[j] = -1;
  }
}

// ------- weight transpose + fp32->bf16: dst[b][c][r] = src[b][r][c] -------
__global__ void transpose_k(const float* __restrict__ src, u16* __restrict__ dst, int R, int C) {
  __shared__ float tile[32][33];
  src += (long)blockIdx.z * R * C;
  dst += (long)blockIdx.z * R * C;
  const int c0 = blockIdx.x * 32, r0 = blockIdx.y * 32;
  const int tx = threadIdx.x & 31, ty = threadIdx.x >> 5;
#pragma unroll
  for (int i = ty; i < 32; i += 8) tile[i][tx] = src[(long)(r0 + i) * C + c0 + tx];
  __syncthreads();
#pragma unroll
  for (int i = ty; i < 32; i += 8) dst[(long)(c0 + i) * R + r0 + tx] = f2bf(tile[tx][i]);
}

// conv_w (I,H,KS) fp32 -> (KS, I, H) bf16
__global__ void convt_k(const float* __restrict__ cw, u16* __restrict__ dst) {
  const int idx = blockIdx.x * 256 + threadIdx.x;
  if (idx >= 3 * 512 * 1024) return;
  const int k = idx >> 19;
  const int rem = idx & 524287;
  const int i = rem >> 10, h = rem & 1023;
  dst[idx] = f2bf(cw[i * 3072 + h * 3 + k]);
}

// ---------------- unified MFMA GEMM ----------------
// LDS layout (u16 index): A row rr (0..127) at rr*32, B row rr at 4096 + rr*32.
// V=0: gathered gate+up, fused silu*up -> inter (128 x 64 out, bf16)
// V=1: expert down (A=inter), fused *tok_w -> Y (128 x 128, bf16)
// V=2: plain C = A @ B^T -> OUT (128 x 128, bf16)
// V=3: conv gate (3 shifted K-phases over xb w/ causal clamp), silu(g)*OUT in-place
// V=4: plain C = A @ B^T -> OUT fp32 (final shared-down)
template<int V>
__global__ __launch_bounds__(256, 2)
void gemm_k(const u16* __restrict__ Abase, const u16* __restrict__ Bt0,
            const u16* __restrict__ Bt1, void* __restrict__ OUTv,
            const int* __restrict__ tbl, const int* __restrict__ nmt,
            const int* __restrict__ tok_ids, const float* __restrict__ tok_w,
            int K, int ldA, int ldOut) {
  __shared__ u16 lds[16384];  // 32 KB
  u16* OUT = (u16*)OUTv;
  float* OUTF = (float*)OUTv;
  const int tid = threadIdx.x;
  const int wave = tid >> 6, lane = tid & 63;
  const int quad = lane >> 4, l16 = lane & 15;
  const int rA = tid >> 2;          // staging row (and +64)
  const int sub8 = (tid & 3) * 8;   // u16 offset inside 32-elem k-slice

  int e = 0, row0, row_end;
  if constexpr (V <= 1) {
    const int mt = blockIdx.x;
    if (mt >= *nmt) return;
    e = tbl[mt * 4]; row0 = tbl[mt * 4 + 1]; row_end = tbl[mt * 4 + 2];
  } else {
    row0 = blockIdx.x * 128; row_end = row0 + 128;
  }
  const int n0 = blockIdx.y * ((V == 0) ? 64 : 128);

  f32x4 acc[2][8];
#pragma unroll
  for (int i = 0; i < 2; ++i)
#pragma unroll
    for (int j = 0; j < 8; ++j) acc[i][j] = (f32x4){0.f, 0.f, 0.f, 0.f};

  const int aoff0 = (wave * 32 + l16) * 32 + quad * 8;
  const int aoff1 = aoff0 + 512;

  const int nph = (V == 3) ? 3 : 1;
  for (int ph = 0; ph < nph; ++ph) {
    const u16 *pA0, *pA1, *pB0, *pB1;
    bool zero0 = false;
    if constexpr (V == 0) {
      const int t0i = tok_ids[min(row0 + rA, row_end - 1)];
      const int t1i = tok_ids[min(row0 + rA + 64, row_end - 1)];
      pA0 = Abase + (long)t0i * 1024 + sub8;
      pA1 = Abase + (long)t1i * 1024 + sub8;
      pB0 = Bt0 + ((long)e * 512 + n0 + rA) * 1024 + sub8;  // gate
      pB1 = Bt1 + ((long)e * 512 + n0 + rA) * 1024 + sub8;  // up
    } else if constexpr (V == 1) {
      pA0 = Abase + (long)min(row0 + rA, row_end - 1) * 512 + sub8;
      pA1 = Abase + (long)min(row0 + rA + 64, row_end - 1) * 512 + sub8;
      pB0 = Bt0 + ((long)e * 1024 + n0 + rA) * 512 + sub8;
      pB1 = Bt0 + ((long)e * 1024 + n0 + rA + 64) * 512 + sub8;
    } else if constexpr (V == 2 || V == 4) {
      pA0 = Abase + (long)(row0 + rA) * ldA + sub8;
      pA1 = Abase + (long)(row0 + rA + 64) * ldA + sub8;
      pB0 = Bt0 + (long)(n0 + rA) * K + sub8;
      pB1 = Bt0 + (long)(n0 + rA + 64) * K + sub8;
    } else {  // V == 3: conv phase ph reads token row s = s0 + rA + ph - 2 (clamped)
      const int bb = row0 >> 12, s0 = row0 & 4095;
      const int si0 = s0 + ph - 2 + rA;
      zero0 = si0 < 0;
      pA0 = Abase + ((long)bb * 4096 + (si0 < 0 ? 0 : si0)) * 1024 + sub8;
      pA1 = Abase + ((long)bb * 4096 + (si0 + 64)) * 1024 + sub8;
      pB0 = Bt0 + (long)ph * 512 * 1024 + (long)(n0 + rA) * 1024 + sub8;
      pB1 = Bt0 + (long)ph * 512 * 1024 + (long)(n0 + rA + 64) * 1024 + sub8;
    }
    const int kIters = K / 32;
    for (int kb = 0; kb < kIters; ++kb) {
      u16x8 va0 = *(const u16x8*)pA0; pA0 += 32;
      u16x8 va1 = *(const u16x8*)pA1; pA1 += 32;
      u16x8 vb0 = *(const u16x8*)pB0; pB0 += 32;
      u16x8 vb1 = *(const u16x8*)pB1; pB1 += 32;
      if constexpr (V == 3) {
        if (zero0) va0 = (u16x8){0, 0, 0, 0, 0, 0, 0, 0};
      }
      __syncthreads();  // prior iteration's ds_reads done; LDS writable
      *(u16x8*)&lds[rA * 32 + sub8] = va0;
      *(u16x8*)&lds[(rA + 64) * 32 + sub8] = va1;
      *(u16x8*)&lds[4096 + rA * 32 + sub8] = vb0;
      *(u16x8*)&lds[4096 + (rA + 64) * 32 + sub8] = vb1;
      __syncthreads();
      bf16x8 a0 = *(const bf16x8*)&lds[aoff0];
      bf16x8 a1 = *(const bf16x8*)&lds[aoff1];
#pragma unroll
      for (int nt = 0; nt < 8; ++nt) {
        bf16x8 b = *(const bf16x8*)&lds[4096 + (nt * 16 + l16) * 32 + quad * 8];
        acc[0][nt] = __builtin_amdgcn_mfma_f32_16x16x32_bf16(a0, b, acc[0][nt], 0, 0, 0);
        acc[1][nt] = __builtin_amdgcn_mfma_f32_16x16x32_bf16(a1, b, acc[1][nt], 0, 0, 0);
      }
    }
  }
  __syncthreads();  // last ds_reads done before epilogue overwrites LDS

  // ---- epilogue ----
  const int rbase = wave * 32;
  if constexpr (V == 0) {
#pragma unroll
    for (int mt = 0; mt < 2; ++mt)
#pragma unroll
      for (int r = 0; r < 4; ++r) {
        const int row = rbase + mt * 16 + quad * 4 + r;
#pragma unroll
        for (int nt = 0; nt < 4; ++nt) {
          float g = acc[mt][nt][r], u = acc[mt][nt + 4][r];
          float sg = g / (1.f + __expf(-g));
          lds[row * 64 + nt * 16 + l16] = f2bf(sg * u);
        }
      }
    __syncthreads();
#pragma unroll
    for (int i = 0; i < 4; ++i) {
      const int c = i * 256 + tid;
      const int row = c >> 3, s8 = (c & 7) * 8;
      const int slot = row0 + row;
      if (slot < row_end)
        *(u16x8*)(OUT + (long)slot * ldOut + n0 + s8) = *(const u16x8*)&lds[row * 64 + s8];
    }
  } else if constexpr (V == 1) {
#pragma unroll
    for (int mt = 0; mt < 2; ++mt)
#pragma unroll
      for (int r = 0; r < 4; ++r) {
        const int row = rbase + mt * 16 + quad * 4 + r;
        const float wgt = tok_w[min(row0 + row, row_end - 1)];
#pragma unroll
        for (int nt = 0; nt < 8; ++nt)
          lds[row * 128 + nt * 16 + l16] = f2bf(acc[mt][nt][r] * wgt);
      }
    __syncthreads();
#pragma unroll
    for (int i = 0; i < 8; ++i) {
      const int c = i * 256 + tid;
      const int row = c >> 4, s8 = (c & 15) * 8;
      const int slot = row0 + row;
      if (slot < row_end)
        *(u16x8*)(OUT + (long)slot * ldOut + n0 + s8) = *(const u16x8*)&lds[row * 128 + s8];
    }
  } else if constexpr (V == 2) {
#pragma unroll
    for (int mt = 0; mt < 2; ++mt)
#pragma unroll
      for (int r = 0; r < 4; ++r) {
        const int row = rbase + mt * 16 + quad * 4 + r;
#pragma unroll
        for (int nt = 0; nt < 8; ++nt)
          lds[row * 128 + nt * 16 + l16] = f2bf(acc[mt][nt][r]);
      }
    __syncthreads();
#pragma unroll
    for (int i = 0; i < 8; ++i) {
      const int c = i * 256 + tid;
      const int row = c >> 4, s8 = (c & 15) * 8;
      *(u16x8*)(OUT + (long)(row0 + row) * ldOut + n0 + s8) = *(const u16x8*)&lds[row * 128 + s8];
    }
  } else if constexpr (V == 3) {  // silu(gate) * OUT -> OUT (OUT holds UP, bf16)
#pragma unroll
    for (int mt = 0; mt < 2; ++mt)
#pragma unroll
      for (int r = 0; r < 4; ++r) {
        const int row = rbase + mt * 16 + quad * 4 + r;
#pragma unroll
        for (int nt = 0; nt < 8; ++nt) {
          float g = acc[mt][nt][r];
          lds[row * 128 + nt * 16 + l16] = f2bf(g / (1.f + __expf(-g)));
        }
      }
    __syncthreads();
#pragma unroll
    for (int i = 0; i < 8; ++i) {
      const int c = i * 256 + tid;
      const int row = c >> 4, s8 = (c & 15) * 8;
      const long o = (long)(row0 + row) * ldOut + n0 + s8;
      u16x8 sg8 = *(const u16x8*)&lds[row * 128 + s8];
      u16x8 up8 = *(const u16x8*)(OUT + o);
      u16x8 res;
#pragma unroll
      for (int j = 0; j < 8; ++j) res[j] = f2bf(bf2f(sg8[j]) * bf2f(up8[j]));
      *(u16x8*)(OUT + o) = res;
    }
  } else {  // V == 4: fp32 direct store
#pragma unroll
    for (int mt = 0; mt < 2; ++mt)
#pragma unroll
      for (int r = 0; r < 4; ++r) {
        const int row = row0 + rbase + mt * 16 + quad * 4 + r;
#pragma unroll
        for (int nt = 0; nt < 8; ++nt)
          OUTF[(long)row * ldOut + n0 + nt * 16 + l16] = acc[mt][nt][r];
      }
  }
}

// ---------------- final combine (fp32) ----------------
__global__ void final_k(const float* __restrict__ x, const u16* __restrict__ Y,
                        const int* __restrict__ slot_map, const float* __restrict__ topk_w,
                        float* __restrict__ out) {
  const long idx = (long)blockIdx.x * 256 + threadIdx.x;  // chunk of 4 over T*1024
  const int t = (int)(idx >> 8), cc = ((int)idx & 255) * 4;
  const long ob = (long)t * 1024 + cc;
  f32x4 o = *(const f32x4*)(out + ob);
#pragma unroll
  for (int k2 = 0; k2 < 2; ++k2) {
    const int sm = slot_map[t * 2 + k2];
    if (sm >= 0) {
      u16x4 y = *(const u16x4*)(Y + (long)sm * 1024 + cc);
#pragma unroll
      for (int j = 0; j < 4; ++j) o[j] += bf2f(y[j]);
    } else {
      const float w = topk_w[t * 2 + k2];
      f32x4 xv = *(const f32x4*)(x + ob);
#pragma unroll
      for (int j = 0; j < 4; ++j) o[j] += w * xv[j];
    }
  }
  *(f32x4*)(out + ob) = o;
}

extern "C" void kernel_launch(void* const* d_in, const int* in_sizes, int n_in,
                              void* d_out, int out_size, void* d_ws, size_t ws_size,
                              hipStream_t stream) {
  (void)in_sizes; (void)n_in; (void)out_size; (void)ws_size;
  const float* x   = (const float*)d_in[0];
  const float* rw  = (const float*)d_in[1];
  const float* rb  = (const float*)d_in[2];
  const float* gw  = (const float*)d_in[3];
  const float* uw  = (const float*)d_in[4];
  const float* dw  = (const float*)d_in[5];
  const float* cw  = (const float*)d_in[6];
  const float* suw = (const float*)d_in[7];
  const float* sdw = (const float*)d_in[8];
  float* out = (float*)d_out;

  char* base = (char*)d_ws;
  size_t off = 0;
  auto alloc = [&](size_t b) { void* p = base + off; off = (off + b + 255) & ~(size_t)255; return p; };
  u16* xb     = (u16*)alloc(16777216ull * 2);
  u16* gate_t = (u16*)alloc(15ull * 512 * 1024 * 2);
  u16* up_t   = (u16*)alloc(15ull * 512 * 1024 * 2);
  u16* down_t = (u16*)alloc(15ull * 1024 * 512 * 2);
  u16* conv_t = (u16*)alloc(3ull * 512 * 1024 * 2);
  u16* sup_t  = (u16*)alloc(512ull * 1024 * 2);
  u16* sdn_t  = (u16*)alloc(512ull * 1024 * 2);
  u16* inter  = (u16*)alloc(32768ull * 512 * 2);
  u16* Y      = (u16*)alloc(32768ull * 1024 * 2);
  u16* UP     = (u16*)alloc(16384ull * 512 * 2);
  int*   topi    = (int*)alloc(32768 * 4);
  float* topw    = (float*)alloc(32768 * 4);
  int*   smap    = (int*)alloc(32768 * 4);
  int*   tok_ids = (int*)alloc(32768 * 4);
  float* tokw    = (float*)alloc(32768 * 4);
  int*   ib      = (int*)alloc(8192);

  zero_k<<<1, 64, 0, stream>>>(ib);
  cvtx_k<<<16384, 256, 0, stream>>>(x, xb);
  transpose_k<<<dim3(16, 32, 15), 256, 0, stream>>>(gw, gate_t, 1024, 512);
  transpose_k<<<dim3(16, 32, 15), 256, 0, stream>>>(uw, up_t, 1024, 512);
  transpose_k<<<dim3(32, 16, 15), 256, 0, stream>>>(dw, down_t, 512, 1024);
  transpose_k<<<dim3(16, 32, 1), 256, 0, stream>>>(suw, sup_t, 1024, 512);
  transpose_k<<<dim3(32, 16, 1), 256, 0, stream>>>(sdw, sdn_t, 512, 1024);
  convt_k<<<6144, 256, 0, stream>>>(cw, conv_t);
  router_k<<<16384, 64, 0, stream>>>(x, rw, rb, topi, topw, ib);
  scan_k<<<1, 64, 0, stream>>>(ib);
  scatter_k<<<128, 256, 0, stream>>>(topi, topw, ib, tok_ids, tokw, smap);
  // routed experts
  gemm_k<0><<<dim3(272, 8), 256, 0, stream>>>(xb, gate_t, up_t, inter, ib + 64, ib + 48,
                                              tok_ids, tokw, 1024, 1024, 512);
  gemm_k<1><<<dim3(272, 8), 256, 0, stream>>>(inter, down_t, nullptr, Y, ib + 64, ib + 48,
                                              nullptr, tokw, 512, 512, 1024);
  // shared expert
  gemm_k<2><<<dim3(128, 4), 256, 0, stream>>>(xb, sup_t, nullptr, UP, nullptr, nullptr,
                                              nullptr, nullptr, 1024, 1024, 512);
  gemm_k<3><<<dim3(128, 4), 256, 0, stream>>>(xb, conv_t, nullptr, UP, nullptr, nullptr,
                                              nullptr, nullptr, 1024, 1024, 512);
  gemm_k<4><<<dim3(128, 8), 256, 0, stream>>>(UP, sdn_t, nullptr, out, nullptr, nullptr,
                                              nullptr, nullptr, 512, 512, 1024);
  final_k<<<16384, 256, 0, stream>>>(x, Y, smap, topw, out);
}

// Round 4
// 610.349 us; speedup vs baseline: 1.6954x; 1.6954x over previous
//
#include <hip/hip_runtime.h>

typedef unsigned short u16;
typedef __attribute__((ext_vector_type(4))) float f32x4;
using bf16x8 = __attribute__((ext_vector_type(8))) short;
typedef __attribute__((ext_vector_type(8))) unsigned short u16x8;
typedef __attribute__((ext_vector_type(4))) unsigned short u16x4;

#define GAS __attribute__((address_space(1)))
#define LAS __attribute__((address_space(3)))

__device__ __forceinline__ float bf2f(u16 u) {
  unsigned v = ((unsigned)u) << 16;
  float f;
  __builtin_memcpy(&f, &v, 4);
  return f;
}
__device__ __forceinline__ u16 f2bf(float f) {
  unsigned u;
  __builtin_memcpy(&u, &f, 4);
  u += 0x7fffu + ((u >> 16) & 1u);
  return (u16)(u >> 16);
}
__device__ __forceinline__ void llds16(const void* g, void* l) {
  __builtin_amdgcn_global_load_lds((const GAS unsigned*)g, (LAS unsigned*)l, 16, 0, 0);
}

// ---------------- x (fp32) -> xb (bf16) ----------------
__global__ void cvtx_k(const float* __restrict__ x, u16* __restrict__ xb) {
  const long i = (long)blockIdx.x * 256 + threadIdx.x;  // chunk of 4
  f32x4 v = *(const f32x4*)(x + i * 4);
  u16x4 r;
#pragma unroll
  for (int j = 0; j < 4; ++j) r[j] = f2bf(v[j]);
  *(u16x4*)(xb + i * 4) = r;
}

// ---------------- router v2: 64 tokens/block, wave = H-slice ----------------
__global__ __launch_bounds__(256) void router_k(const float* __restrict__ x,
    const float* __restrict__ rw, const float* __restrict__ rb,
    int* __restrict__ topk_idx, float* __restrict__ topk_w, int* __restrict__ ib) {
  __shared__ float xs[4][32 * 65];    // [wave][h*65 + tok]
  __shared__ float wsm[4][32 * 16];   // [wave][h*16 + e]
  __shared__ float part[4][64 * 17];  // [wave][tok*17 + e]
  __shared__ int cnt[16];
  const int tid = threadIdx.x;
  const int wv = __builtin_amdgcn_readfirstlane(tid >> 6);
  const int lane = tid & 63;
  const int tok0 = blockIdx.x * 64;
  const int rr = lane >> 3;       // row-sub 0..7
  const int c4 = (lane & 7) * 4;  // col within 32-h chunk

  float acc[16];
#pragma unroll
  for (int e = 0; e < 16; ++e) acc[e] = 0.f;

  for (int c = 0; c < 8; ++c) {
    const int hb = wv * 256 + c * 32;
    // stage w chunk (512 contiguous floats)
    {
      f32x4 wa = *(const f32x4*)(rw + hb * 16 + lane * 4);
      f32x4 wb = *(const f32x4*)(rw + hb * 16 + 256 + lane * 4);
      *(f32x4*)&wsm[wv][lane * 4] = wa;
      *(f32x4*)&wsm[wv][256 + lane * 4] = wb;
    }
    // stage x chunk transposed: rows tok0..+63, cols hb..hb+31 -> xs[h][tok]
#pragma unroll
    for (int i = 0; i < 8; ++i) {
      const int row = i * 8 + rr;
      f32x4 v = *(const f32x4*)(x + (long)(tok0 + row) * 1024 + hb + c4);
#pragma unroll
      for (int j = 0; j < 4; ++j) xs[wv][(c4 + j) * 65 + row] = v[j];
    }
    __syncthreads();
#pragma unroll
    for (int h = 0; h < 32; ++h) {
      const float xv = xs[wv][h * 65 + lane];
      const float* wrow = &wsm[wv][h * 16];
#pragma unroll
      for (int q = 0; q < 4; ++q) {
        f32x4 w4 = *(const f32x4*)(wrow + q * 4);
#pragma unroll
        for (int e = 0; e < 4; ++e) acc[q * 4 + e] += xv * w4[e];
      }
    }
    __syncthreads();
  }
#pragma unroll
  for (int e = 0; e < 16; ++e) part[wv][lane * 17 + e] = acc[e];
  if (tid < 16) cnt[tid] = 0;
  __syncthreads();
  if (tid < 64) {
    float p[16];
#pragma unroll
    for (int e = 0; e < 16; ++e)
      p[e] = part[0][tid * 17 + e] + part[1][tid * 17 + e] +
             part[2][tid * 17 + e] + part[3][tid * 17 + e] + rb[e];
    float mx = p[0];
#pragma unroll
    for (int e = 1; e < 16; ++e) mx = fmaxf(mx, p[e]);
    float sum = 0.f;
#pragma unroll
    for (int e = 0; e < 16; ++e) { p[e] = __expf(p[e] - mx); sum += p[e]; }
    int i0 = 0; float p0 = p[0];
    for (int e = 1; e < 16; ++e) if (p[e] > p0) { p0 = p[e]; i0 = e; }
    int i1 = -1; float p1 = -1.f;
    for (int e = 0; e < 16; ++e) if (e != i0 && p[e] > p1) { p1 = p[e]; i1 = e; }
    const float inv = 1.f / sum;
    p0 *= inv; p1 *= inv;
    const float d = p0 + p1 + 1e-6f;
    const int t = tok0 + tid;
    topk_idx[t * 2] = i0; topk_idx[t * 2 + 1] = i1;
    topk_w[t * 2] = p0 / d;
    topk_w[t * 2 + 1] = p1 / d;
    if (i0 < 15) atomicAdd(&cnt[i0], 1);
    if (i1 < 15) atomicAdd(&cnt[i1], 1);
  }
  __syncthreads();
  if (tid < 15 && cnt[tid] > 0) atomicAdd(&ib[tid], cnt[tid]);
}

// ib layout: [0..15] counts, [16..31] offsets (offs[15]=total), [32..47] cursors,
//            [48] n_mtiles, [64..] mtile table {expert,row0,row_end,pad}
__global__ void zero_k(int* __restrict__ ib) {
  if (threadIdx.x < 16) ib[threadIdx.x] = 0;
}

__global__ void scan_k(int* __restrict__ ib) {
  if (threadIdx.x != 0 || blockIdx.x != 0) return;
  int off = 0;
  for (int ee = 0; ee < 15; ++ee) { ib[16 + ee] = off; ib[32 + ee] = off; off += ib[ee]; }
  ib[16 + 15] = off;
  int nm = 0;
  for (int ee = 0; ee < 15; ++ee) {
    const int st = ib[16 + ee], en = ib[16 + ee + 1];
    for (int r = st; r < en; r += 128) {
      ib[64 + nm * 4] = ee; ib[64 + nm * 4 + 1] = r; ib[64 + nm * 4 + 2] = en; ++nm;
    }
  }
  ib[48] = nm;
}

// scatter v2: per-block LDS aggregation, 15 global atomics/block
__global__ __launch_bounds__(256) void scatter_k(const int* __restrict__ topk_idx,
                          const float* __restrict__ topk_w,
                          int* __restrict__ ib, int* __restrict__ tok_ids,
                          float* __restrict__ tok_w, int* __restrict__ slot_map) {
  __shared__ int cnt[16], base[16];
  const int tid = threadIdx.x;
  const int j = blockIdx.x * 256 + tid;
  if (tid < 16) cnt[tid] = 0;
  __syncthreads();
  const int e = topk_idx[j];
  int lo = 0;
  if (e < 15) lo = atomicAdd(&cnt[e], 1);
  __syncthreads();
  if (tid < 15 && cnt[tid] > 0) base[tid] = atomicAdd(&ib[32 + tid], cnt[tid]);
  __syncthreads();
  if (e < 15) {
    const int pos = base[e] + lo;
    tok_ids[pos] = j >> 1;
    tok_w[pos] = topk_w[j];
    slot_map[j] = pos;
  } else {
    slot_map[j] = -1;
  }
}

// ------- weight transpose + fp32->bf16: dst[b][c][r] = src[b][r][c] -------
__global__ void transpose_k(const float* __restrict__ src, u16* __restrict__ dst, int R, int C) {
  __shared__ float tile[32][33];
  src += (long)blockIdx.z * R * C;
  dst += (long)blockIdx.z * R * C;
  const int c0 = blockIdx.x * 32, r0 = blockIdx.y * 32;
  const int tx = threadIdx.x & 31, ty = threadIdx.x >> 5;
#pragma unroll
  for (int i = ty; i < 32; i += 8) tile[i][tx] = src[(long)(r0 + i) * C + c0 + tx];
  __syncthreads();
#pragma unroll
  for (int i = ty; i < 32; i += 8) dst[(long)(c0 + i) * R + r0 + tx] = f2bf(tile[tx][i]);
}

// conv_w (I,H,KS) fp32 -> (KS, I, H) bf16
__global__ void convt_k(const float* __restrict__ cw, u16* __restrict__ dst) {
  const int idx = blockIdx.x * 256 + threadIdx.x;
  if (idx >= 3 * 512 * 1024) return;
  const int k = idx >> 19;
  const int rem = idx & 524287;
  const int i = rem >> 10, h = rem & 1023;
  dst[idx] = f2bf(cw[i * 3072 + h * 3 + k]);
}

// ---------------- unified MFMA GEMM ----------------
// LDS layout (u16 index): A row rr (0..127) at rr*32, B row rr at 4096 + rr*32.
// V=0: gathered gate+up, fused silu*up -> inter (128 x 64 out, bf16)
// V=1: expert down (A=inter), fused *tok_w -> Y (128 x 128, bf16)
// V=2: plain C = A @ B^T -> OUT (128 x 128, bf16)
// V=3: conv gate (3 shifted K-phases over xb w/ causal clamp), silu(g)*OUT in-place
// V=4: plain C = A @ B^T -> OUT fp32 (final shared-down)
template<int V>
__global__ __launch_bounds__(256, 2)
void gemm_k(const u16* __restrict__ Abase, const u16* __restrict__ Bt0,
            const u16* __restrict__ Bt1, void* __restrict__ OUTv,
            const int* __restrict__ tbl, const int* __restrict__ nmt,
            const int* __restrict__ tok_ids, const float* __restrict__ tok_w,
            int K, int ldA, int ldOut) {
  __shared__ u16 lds[16384];  // 32 KB
  u16* OUT = (u16*)OUTv;
  float* OUTF = (float*)OUTv;
  const int tid = threadIdx.x;
  const int wave = tid >> 6, lane = tid & 63;
  const int quad = lane >> 4, l16 = lane & 15;
  const int rA = tid >> 2;          // staging row (and +64)
  const int sub8 = (tid & 3) * 8;   // u16 offset inside 32-elem k-slice

  int e = 0, row0, row_end;
  if constexpr (V <= 1) {
    const int mt = blockIdx.x;
    if (mt >= *nmt) return;
    e = tbl[mt * 4]; row0 = tbl[mt * 4 + 1]; row_end = tbl[mt * 4 + 2];
  } else {
    row0 = blockIdx.x * 128; row_end = row0 + 128;
  }
  const int n0 = blockIdx.y * ((V == 0) ? 64 : 128);

  f32x4 acc[2][8];
#pragma unroll
  for (int i = 0; i < 2; ++i)
#pragma unroll
    for (int j = 0; j < 8; ++j) acc[i][j] = (f32x4){0.f, 0.f, 0.f, 0.f};

  const int aoff0 = (wave * 32 + l16) * 32 + quad * 8;
  const int aoff1 = aoff0 + 512;
  // wave-uniform LDS staging bases for global_load_lds (dest = base + lane*16B)
  u16* ldsA0 = &lds[wave * 512];
  u16* ldsA1 = &lds[2048 + wave * 512];
  u16* ldsB0 = &lds[4096 + wave * 512];
  u16* ldsB1 = &lds[6144 + wave * 512];

  const int nph = (V == 3) ? 3 : 1;
  for (int ph = 0; ph < nph; ++ph) {
    const u16 *pA0, *pA1, *pB0, *pB1;
    bool zero0 = false;
    if constexpr (V == 0) {
      const int t0i = tok_ids[min(row0 + rA, row_end - 1)];
      const int t1i = tok_ids[min(row0 + rA + 64, row_end - 1)];
      pA0 = Abase + (long)t0i * 1024 + sub8;
      pA1 = Abase + (long)t1i * 1024 + sub8;
      pB0 = Bt0 + ((long)e * 512 + n0 + rA) * 1024 + sub8;  // gate
      pB1 = Bt1 + ((long)e * 512 + n0 + rA) * 1024 + sub8;  // up
    } else if constexpr (V == 1) {
      pA0 = Abase + (long)min(row0 + rA, row_end - 1) * 512 + sub8;
      pA1 = Abase + (long)min(row0 + rA + 64, row_end - 1) * 512 + sub8;
      pB0 = Bt0 + ((long)e * 1024 + n0 + rA) * 512 + sub8;
      pB1 = Bt0 + ((long)e * 1024 + n0 + rA + 64) * 512 + sub8;
    } else if constexpr (V == 2 || V == 4) {
      pA0 = Abase + (long)(row0 + rA) * ldA + sub8;
      pA1 = Abase + (long)(row0 + rA + 64) * ldA + sub8;
      pB0 = Bt0 + (long)(n0 + rA) * K + sub8;
      pB1 = Bt0 + (long)(n0 + rA + 64) * K + sub8;
    } else {  // V == 3: conv phase ph reads token row s = s0 + rA + ph - 2 (clamped)
      const int bb = row0 >> 12, s0 = row0 & 4095;
      const int si0 = s0 + ph - 2 + rA;
      zero0 = si0 < 0;
      pA0 = Abase + ((long)bb * 4096 + (si0 < 0 ? 0 : si0)) * 1024 + sub8;
      pA1 = Abase + ((long)bb * 4096 + (si0 + 64)) * 1024 + sub8;
      pB0 = Bt0 + (long)ph * 512 * 1024 + (long)(n0 + rA) * 1024 + sub8;
      pB1 = Bt0 + (long)ph * 512 * 1024 + (long)(n0 + rA + 64) * 1024 + sub8;
    }
    const int kIters = K / 32;
    for (int kb = 0; kb < kIters; ++kb) {
      u16x8 va0, va1;
      if constexpr (V == 3) {
        va0 = *(const u16x8*)pA0; pA0 += 32;
        va1 = *(const u16x8*)pA1; pA1 += 32;
        if (zero0) va0 = (u16x8){0, 0, 0, 0, 0, 0, 0, 0};
      }
      __syncthreads();  // all waves done reading previous tile
      if constexpr (V == 3) {
        *(u16x8*)&lds[rA * 32 + sub8] = va0;
        *(u16x8*)&lds[(rA + 64) * 32 + sub8] = va1;
      } else {
        llds16(pA0, ldsA0); pA0 += 32;
        llds16(pA1, ldsA1); pA1 += 32;
      }
      llds16(pB0, ldsB0); pB0 += 32;
      llds16(pB1, ldsB1); pB1 += 32;
      __syncthreads();  // drains vmcnt/lgkmcnt: staged tile visible
      bf16x8 a0 = *(const bf16x8*)&lds[aoff0];
      bf16x8 a1 = *(const bf16x8*)&lds[aoff1];
#pragma unroll
      for (int nt = 0; nt < 8; ++nt) {
        bf16x8 b = *(const bf16x8*)&lds[4096 + (nt * 16 + l16) * 32 + quad * 8];
        acc[0][nt] = __builtin_amdgcn_mfma_f32_16x16x32_bf16(a0, b, acc[0][nt], 0, 0, 0);
        acc[1][nt] = __builtin_amdgcn_mfma_f32_16x16x32_bf16(a1, b, acc[1][nt], 0, 0, 0);
      }
    }
  }
  __syncthreads();  // last ds_reads done before epilogue overwrites LDS

  // ---- epilogue ----
  const int rbase = wave * 32;
  if constexpr (V == 0) {
#pragma unroll
    for (int mt = 0; mt < 2; ++mt)
#pragma unroll
      for (int r = 0; r < 4; ++r) {
        const int row = rbase + mt * 16 + quad * 4 + r;
#pragma unroll
        for (int nt = 0; nt < 4; ++nt) {
          float g = acc[mt][nt][r], u = acc[mt][nt + 4][r];
          float sg = g / (1.f + __expf(-g));
          lds[row * 64 + nt * 16 + l16] = f2bf(sg * u);
        }
      }
    __syncthreads();
#pragma unroll
    for (int i = 0; i < 4; ++i) {
      const int c = i * 256 + tid;
      const int row = c >> 3, s8 = (c & 7) * 8;
      const int slot = row0 + row;
      if (slot < row_end)
        *(u16x8*)(OUT + (long)slot * ldOut + n0 + s8) = *(const u16x8*)&lds[row * 64 + s8];
    }
  } else if constexpr (V == 1) {
#pragma unroll
    for (int mt = 0; mt < 2; ++mt)
#pragma unroll
      for (int r = 0; r < 4; ++r) {
        const int row = rbase + mt * 16 + quad * 4 + r;
        const float wgt = tok_w[min(row0 + row, row_end - 1)];
#pragma unroll
        for (int nt = 0; nt < 8; ++nt)
          lds[row * 128 + nt * 16 + l16] = f2bf(acc[mt][nt][r] * wgt);
      }
    __syncthreads();
#pragma unroll
    for (int i = 0; i < 8; ++i) {
      const int c = i * 256 + tid;
      const int row = c >> 4, s8 = (c & 15) * 8;
      const int slot = row0 + row;
      if (slot < row_end)
        *(u16x8*)(OUT + (long)slot * ldOut + n0 + s8) = *(const u16x8*)&lds[row * 128 + s8];
    }
  } else if constexpr (V == 2) {
#pragma unroll
    for (int mt = 0; mt < 2; ++mt)
#pragma unroll
      for (int r = 0; r < 4; ++r) {
        const int row = rbase + mt * 16 + quad * 4 + r;
#pragma unroll
        for (int nt = 0; nt < 8; ++nt)
          lds[row * 128 + nt * 16 + l16] = f2bf(acc[mt][nt][r]);
      }
    __syncthreads();
#pragma unroll
    for (int i = 0; i < 8; ++i) {
      const int c = i * 256 + tid;
      const int row = c >> 4, s8 = (c & 15) * 8;
      *(u16x8*)(OUT + (long)(row0 + row) * ldOut + n0 + s8) = *(const u16x8*)&lds[row * 128 + s8];
    }
  } else if constexpr (V == 3) {  // silu(gate) * OUT -> OUT (OUT holds UP, bf16)
#pragma unroll
    for (int mt = 0; mt < 2; ++mt)
#pragma unroll
      for (int r = 0; r < 4; ++r) {
        const int row = rbase + mt * 16 + quad * 4 + r;
#pragma unroll
        for (int nt = 0; nt < 8; ++nt) {
          float g = acc[mt][nt][r];
          lds[row * 128 + nt * 16 + l16] = f2bf(g / (1.f + __expf(-g)));
        }
      }
    __syncthreads();
#pragma unroll
    for (int i = 0; i < 8; ++i) {
      const int c = i * 256 + tid;
      const int row = c >> 4, s8 = (c & 15) * 8;
      const long o = (long)(row0 + row) * ldOut + n0 + s8;
      u16x8 sg8 = *(const u16x8*)&lds[row * 128 + s8];
      u16x8 up8 = *(const u16x8*)(OUT + o);
      u16x8 res;
#pragma unroll
      for (int j = 0; j < 8; ++j) res[j] = f2bf(bf2f(sg8[j]) * bf2f(up8[j]));
      *(u16x8*)(OUT + o) = res;
    }
  } else {  // V == 4: fp32 direct store
#pragma unroll
    for (int mt = 0; mt < 2; ++mt)
#pragma unroll
      for (int r = 0; r < 4; ++r) {
        const int row = row0 + rbase + mt * 16 + quad * 4 + r;
#pragma unroll
        for (int nt = 0; nt < 8; ++nt)
          OUTF[(long)row * ldOut + n0 + nt * 16 + l16] = acc[mt][nt][r];
      }
  }
}

// ---------------- final combine (fp32) ----------------
__global__ void final_k(const float* __restrict__ x, const u16* __restrict__ Y,
                        const int* __restrict__ slot_map, const float* __restrict__ topk_w,
                        float* __restrict__ out) {
  const long idx = (long)blockIdx.x * 256 + threadIdx.x;  // chunk of 4 over T*1024
  const int t = (int)(idx >> 8), cc = ((int)idx & 255) * 4;
  const long ob = (long)t * 1024 + cc;
  f32x4 o = *(const f32x4*)(out + ob);
#pragma unroll
  for (int k2 = 0; k2 < 2; ++k2) {
    const int sm = slot_map[t * 2 + k2];
    if (sm >= 0) {
      u16x4 y = *(const u16x4*)(Y + (long)sm * 1024 + cc);
#pragma unroll
      for (int j = 0; j < 4; ++j) o[j] += bf2f(y[j]);
    } else {
      const float w = topk_w[t * 2 + k2];
      f32x4 xv = *(const f32x4*)(x + ob);
#pragma unroll
      for (int j = 0; j < 4; ++j) o[j] += w * xv[j];
    }
  }
  *(f32x4*)(out + ob) = o;
}

extern "C" void kernel_launch(void* const* d_in, const int* in_sizes, int n_in,
                              void* d_out, int out_size, void* d_ws, size_t ws_size,
                              hipStream_t stream) {
  (void)in_sizes; (void)n_in; (void)out_size; (void)ws_size;
  const float* x   = (const float*)d_in[0];
  const float* rw  = (const float*)d_in[1];
  const float* rb  = (const float*)d_in[2];
  const float* gw  = (const float*)d_in[3];
  const float* uw  = (const float*)d_in[4];
  const float* dw  = (const float*)d_in[5];
  const float* cw  = (const float*)d_in[6];
  const float* suw = (const float*)d_in[7];
  const float* sdw = (const float*)d_in[8];
  float* out = (float*)d_out;

  char* base = (char*)d_ws;
  size_t off = 0;
  auto alloc = [&](size_t b) { void* p = base + off; off = (off + b + 255) & ~(size_t)255; return p; };
  u16* xb     = (u16*)alloc(16777216ull * 2);
  u16* gate_t = (u16*)alloc(15ull * 512 * 1024 * 2);
  u16* up_t   = (u16*)alloc(15ull * 512 * 1024 * 2);
  u16* down_t = (u16*)alloc(15ull * 1024 * 512 * 2);
  u16* conv_t = (u16*)alloc(3ull * 512 * 1024 * 2);
  u16* sup_t  = (u16*)alloc(512ull * 1024 * 2);
  u16* sdn_t  = (u16*)alloc(512ull * 1024 * 2);
  u16* inter  = (u16*)alloc(32768ull * 512 * 2);
  u16* Y      = (u16*)alloc(32768ull * 1024 * 2);
  u16* UP     = (u16*)alloc(16384ull * 512 * 2);
  int*   topi    = (int*)alloc(32768 * 4);
  float* topw    = (float*)alloc(32768 * 4);
  int*   smap    = (int*)alloc(32768 * 4);
  int*   tok_ids = (int*)alloc(32768 * 4);
  float* tokw    = (float*)alloc(32768 * 4);
  int*   ib      = (int*)alloc(8192);

  zero_k<<<1, 64, 0, stream>>>(ib);
  cvtx_k<<<16384, 256, 0, stream>>>(x, xb);
  transpose_k<<<dim3(16, 32, 15), 256, 0, stream>>>(gw, gate_t, 1024, 512);
  transpose_k<<<dim3(16, 32, 15), 256, 0, stream>>>(uw, up_t, 1024, 512);
  transpose_k<<<dim3(32, 16, 15), 256, 0, stream>>>(dw, down_t, 512, 1024);
  transpose_k<<<dim3(16, 32, 1), 256, 0, stream>>>(suw, sup_t, 1024, 512);
  transpose_k<<<dim3(32, 16, 1), 256, 0, stream>>>(sdw, sdn_t, 512, 1024);
  convt_k<<<6144, 256, 0, stream>>>(cw, conv_t);
  router_k<<<256, 256, 0, stream>>>(x, rw, rb, topi, topw, ib);
  scan_k<<<1, 64, 0, stream>>>(ib);
  scatter_k<<<128, 256, 0, stream>>>(topi, topw, ib, tok_ids, tokw, smap);
  // routed experts
  gemm_k<0><<<dim3(272, 8), 256, 0, stream>>>(xb, gate_t, up_t, inter, ib + 64, ib + 48,
                                              tok_ids, tokw, 1024, 1024, 512);
  gemm_k<1><<<dim3(272, 8), 256, 0, stream>>>(inter, down_t, nullptr, Y, ib + 64, ib + 48,
                                              nullptr, tokw, 512, 512, 1024);
  // shared expert
  gemm_k<2><<<dim3(128, 4), 256, 0, stream>>>(xb, sup_t, nullptr, UP, nullptr, nullptr,
                                              nullptr, nullptr, 1024, 1024, 512);
  gemm_k<3><<<dim3(128, 4), 256, 0, stream>>>(xb, conv_t, nullptr, UP, nullptr, nullptr,
                                              nullptr, nullptr, 1024, 1024, 512);
  gemm_k<4><<<dim3(128, 8), 256, 0, stream>>>(UP, sdn_t, nullptr, out, nullptr, nullptr,
                                              nullptr, nullptr, 512, 512, 1024);
  final_k<<<16384, 256, 0, stream>>>(x, Y, smap, topw, out);
}